// Round 1
// baseline (122.401 us; speedup 1.0000x reference)
//
#include <hip/hip_runtime.h>
#include <hip/hip_bf16.h>

typedef __attribute__((ext_vector_type(8))) __bf16 bf16x8;
typedef __attribute__((ext_vector_type(4))) __bf16 bf16x4;
typedef __attribute__((ext_vector_type(4))) float  f32x4;

#define S_  2048
#define D_  128
#define QB  128   // q rows per block (4 waves x 32)
#define KB  32    // kv rows per iteration
#define NW  4

__device__ __forceinline__ __bf16 f2bf(float f) { return (__bf16)f; }

__global__ __launch_bounds__(256, 2)
void attn_fwd(const float* __restrict__ Q, const float* __restrict__ K,
              const float* __restrict__ V, float* __restrict__ O) {
    // K tile row-major, rows padded to 136 elems (272B = 17*16B: aligned, 2-way banks)
    __shared__ __align__(16) __bf16 k_lds[KB][136];
    // V tile transposed: vt[d][kk], kk padded to 40; kk-blocks XOR-swizzled by (d>>4)&3
    __shared__ __align__(16) __bf16 vt_lds[D_][40];
    // per-wave P^T: [q(16)][kk(32)+pad8]
    __shared__ __align__(16) __bf16 p_lds[NW][2][16][40];

    const int t   = threadIdx.x;
    const int w   = t >> 6;
    const int l   = t & 63;
    const int l16 = l & 15;
    const int lg  = l >> 4;

    // XCD-aware remap: all 16 q-blocks of a batch land on one XCD (K/V L2-resident)
    const int f  = blockIdx.x + (int)gridDim.x * blockIdx.y;   // 0..511
    const int b  = ((f & 7) << 2) | ((f >> 3) & 3);            // batch
    const int bq = f >> 5;                                     // q-block

    const int q0 = bq * QB + w * 32;
    const float scale = 0.08838834764831845f;  // 1/sqrt(128)

    const float* Qb = Q + (size_t)b * S_ * D_;
    const float* Kb = K + (size_t)b * S_ * D_;
    const float* Vb = V + (size_t)b * S_ * D_;

    // ---- Q fragments, B-operand layout: col q = l16, k = d = lg*8 + j ----
    bf16x8 qf[2][4];
    #pragma unroll
    for (int qt = 0; qt < 2; ++qt) {
        const float* qrow = Qb + (size_t)(q0 + qt * 16 + l16) * D_;
        #pragma unroll
        for (int ds = 0; ds < 4; ++ds) {
            const float4* p4 = (const float4*)(qrow + ds * 32 + lg * 8);
            float4 a = p4[0], c = p4[1];
            bf16x8 fv;
            fv[0]=f2bf(a.x); fv[1]=f2bf(a.y); fv[2]=f2bf(a.z); fv[3]=f2bf(a.w);
            fv[4]=f2bf(c.x); fv[5]=f2bf(c.y); fv[6]=f2bf(c.z); fv[7]=f2bf(c.w);
            qf[qt][ds] = fv;
        }
    }

    f32x4 acc[2][8];
    #pragma unroll
    for (int qt = 0; qt < 2; ++qt)
        #pragma unroll
        for (int dt = 0; dt < 8; ++dt)
            acc[qt][dt] = (f32x4){0.f, 0.f, 0.f, 0.f};
    float den[2] = {0.f, 0.f};

    const int sr = t >> 3;         // staging row 0..31
    const int sc = (t & 7) * 16;   // staging col base

    for (int kk0 = 0; kk0 < S_; kk0 += KB) {
        // ---- stage K (row-major) and V (transposed + swizzled), fp32->bf16 ----
        const float4* kp = (const float4*)(Kb + (size_t)(kk0 + sr) * D_ + sc);
        const float4* vp = (const float4*)(Vb + (size_t)(kk0 + sr) * D_ + sc);
        float4 k0 = kp[0], k1 = kp[1], k2 = kp[2], k3 = kp[3];
        float4 v0 = vp[0], v1 = vp[1], v2 = vp[2], v3 = vp[3];

        bf16x8 ka, kc;
        ka[0]=f2bf(k0.x); ka[1]=f2bf(k0.y); ka[2]=f2bf(k0.z); ka[3]=f2bf(k0.w);
        ka[4]=f2bf(k1.x); ka[5]=f2bf(k1.y); ka[6]=f2bf(k1.z); ka[7]=f2bf(k1.w);
        kc[0]=f2bf(k2.x); kc[1]=f2bf(k2.y); kc[2]=f2bf(k2.z); kc[3]=f2bf(k2.w);
        kc[4]=f2bf(k3.x); kc[5]=f2bf(k3.y); kc[6]=f2bf(k3.z); kc[7]=f2bf(k3.w);
        *(bf16x8*)&k_lds[sr][sc]     = ka;
        *(bf16x8*)&k_lds[sr][sc + 8] = kc;

        float vv[16] = {v0.x,v0.y,v0.z,v0.w, v1.x,v1.y,v1.z,v1.w,
                        v2.x,v2.y,v2.z,v2.w, v3.x,v3.y,v3.z,v3.w};
        #pragma unroll
        for (int i = 0; i < 16; ++i) {
            const int d   = sc + i;
            const int blk = (sr >> 3) ^ ((d >> 4) & 3);   // swizzled kk-block
            vt_lds[d][blk * 8 + (sr & 7)] = f2bf(vv[i]);
        }
        __syncthreads();

        // ---- S^T = K * Q^T  -> exp -> P^T to LDS ----
        #pragma unroll
        for (int ct = 0; ct < 2; ++ct) {
            bf16x8 kf[4];
            #pragma unroll
            for (int ds = 0; ds < 4; ++ds)
                kf[ds] = *(const bf16x8*)&k_lds[ct * 16 + l16][ds * 32 + lg * 8];
            #pragma unroll
            for (int qt = 0; qt < 2; ++qt) {
                f32x4 s = {0.f, 0.f, 0.f, 0.f};
                #pragma unroll
                for (int ds = 0; ds < 4; ++ds)
                    s = __builtin_amdgcn_mfma_f32_16x16x32_bf16(kf[ds], qf[qt][ds], s, 0, 0, 0);
                // lane holds: q = q0+qt*16+l16 (col), kk = kk0+ct*16+lg*4+r (row)
                bf16x4 pp;
                float psum = 0.f;
                #pragma unroll
                for (int r = 0; r < 4; ++r) {
                    float e = __expf(s[r] * scale);
                    psum += e;
                    pp[r] = f2bf(e);
                }
                den[qt] += psum;
                *(bf16x4*)&p_lds[w][qt][l16][ct * 16 + lg * 4] = pp;
            }
        }

        // ---- O^T += V^T * P^T ----
        bf16x8 vf[8];
        #pragma unroll
        for (int dt = 0; dt < 8; ++dt)
            vf[dt] = *(const bf16x8*)&vt_lds[dt * 16 + l16][(lg ^ (dt & 3)) * 8];
        #pragma unroll
        for (int qt = 0; qt < 2; ++qt) {
            bf16x8 pf = *(const bf16x8*)&p_lds[w][qt][l16][lg * 8];
            #pragma unroll
            for (int dt = 0; dt < 8; ++dt)
                acc[qt][dt] = __builtin_amdgcn_mfma_f32_16x16x32_bf16(vf[dt], pf, acc[qt][dt], 0, 0, 0);
        }
        __syncthreads();
    }

    // ---- finalize: den butterfly over lane bits 4,5; divide; store ----
    #pragma unroll
    for (int qt = 0; qt < 2; ++qt) {
        float dsum = den[qt];
        dsum += __shfl_xor(dsum, 16);
        dsum += __shfl_xor(dsum, 32);
        const float inv = 1.0f / dsum;
        float* orow = O + (size_t)b * S_ * D_ + (size_t)(q0 + qt * 16 + l16) * D_;
        #pragma unroll
        for (int dt = 0; dt < 8; ++dt) {
            #pragma unroll
            for (int r = 0; r < 4; ++r)
                orow[dt * 16 + lg * 4 + r] = acc[qt][dt][r] * inv;
        }
    }
}

extern "C" void kernel_launch(void* const* d_in, const int* in_sizes, int n_in,
                              void* d_out, int out_size, void* d_ws, size_t ws_size,
                              hipStream_t stream) {
    const float* q = (const float*)d_in[0];
    const float* k = (const float*)d_in[1];
    const float* v = (const float*)d_in[2];
    float* o = (float*)d_out;
    dim3 grid(S_ / QB, 32);
    dim3 block(256);
    attn_fwd<<<grid, block, 0, stream>>>(q, k, v, o);
}